// Round 21
// baseline (105.207 us; speedup 1.0000x reference)
//
#include <hip/hip_runtime.h>
#include <cstdint>
#include <cstddef>

// Fused Swin-style window attention for MI355X (gfx950), round 21.
// R20 (101us): R17 structure + setprio + raw exp2 + load-order. All pipes <41%
// -> residual is critical-path stall. Last unhoisted latency: qkv weight loads
// (12 x 16B per wave) issued inline in the unrolled ks loop, feeding that
// iteration's MFMAs. R21 hoists them to block start (after x HBM loads, before
// stage conversion) so their L2 latency hides under stage VALU + barrier B1.
// Reg math: qkv peak ~120 < 128 cap of (512,4). Tripwire: FETCH/WRITE
// inflation = spill = revert.

typedef float f32x4 __attribute__((ext_vector_type(4)));
typedef __bf16 bf16x8 __attribute__((ext_vector_type(8)));
typedef unsigned short u16x8 __attribute__((ext_vector_type(8)));
typedef unsigned short u16x4 __attribute__((ext_vector_type(4)));

__device__ __forceinline__ unsigned short bfs(float f) {
  return __builtin_bit_cast(unsigned short, (__bf16)f);  // HW RNE cvt
}
__device__ __forceinline__ unsigned pk2n(float a, float b) {
  return (unsigned)bfs(a) | ((unsigned)bfs(b) << 16);
}
__device__ __forceinline__ uint2 pku2(f32x4 v) {
  uint2 r; r.x = pk2n(v[0], v[1]); r.y = pk2n(v[2], v[3]); return r;
}
__device__ __forceinline__ u16x8 pack8(f32x4 a, f32x4 b) {
  u16x8 r;
  r[0] = bfs(a[0]); r[1] = bfs(a[1]); r[2] = bfs(a[2]); r[3] = bfs(a[3]);
  r[4] = bfs(b[0]); r[5] = bfs(b[1]); r[6] = bfs(b[2]); r[7] = bfs(b[3]);
  return r;
}
__device__ __forceinline__ f32x4 bf4up(u16x4 v) {
  f32x4 r;
  r[0] = __builtin_bit_cast(float, (unsigned)v[0] << 16);
  r[1] = __builtin_bit_cast(float, (unsigned)v[1] << 16);
  r[2] = __builtin_bit_cast(float, (unsigned)v[2] << 16);
  r[3] = __builtin_bit_cast(float, (unsigned)v[3] << 16);
  return r;
}
__device__ __forceinline__ f32x4 mfma32(u16x8 a, u16x8 b, f32x4 c) {
  return __builtin_amdgcn_mfma_f32_16x16x32_bf16(
      __builtin_bit_cast(bf16x8, a), __builtin_bit_cast(bf16x8, b), c, 0, 0, 0);
}

// ---------------- prep: weights^T -> bf16, rel-pos bias -> bf16 frag layout ----------
// ws: [0,98304)        wqkv_t bf16 [384 cols][128 k]   (Q cols scaled by log2e/sqrt(hd))
//     [98304,131072)   wproj_t bf16 [128 cols][128 k]
//     [131072,163840)  bias bf16 [h][qh][mk][nq][lane][i]  (S^T frag layout, * log2e)
__global__ void prep_kernel(const float* __restrict__ wqkv, const float* __restrict__ wproj,
                            const float* __restrict__ btab,
                            unsigned short* __restrict__ wqkvt,
                            unsigned short* __restrict__ wprojt,
                            unsigned short* __restrict__ biasbf) {
  int t = blockIdx.x * 256 + threadIdx.x;
  if (t < 49152) {
    int c = t >> 7, k = t & 127;
    float v = wqkv[k * 384 + c];
    if (c < 128) v *= 0.25503486f;  // log2(e)/sqrt(32)
    wqkvt[t] = bfs(v);
  } else if (t < 65536) {
    int t2 = t - 49152;
    int c = t2 >> 7, k = t2 & 127;
    wprojt[t2] = bfs(wproj[k * 128 + c]);
  } else if (t < 81920) {
    int t3 = t - 65536;
    int i = t3 & 3, lane = (t3 >> 2) & 63;
    int nq = (t3 >> 8) & 1, mk = (t3 >> 9) & 3, qh = (t3 >> 11) & 1, h = (t3 >> 12) & 3;
    int key = mk * 16 + ((lane >> 4) << 2) + i;      // S^T row (C-layout)
    int q   = qh * 32 + nq * 16 + (lane & 15);       // S^T col
    int idx = ((q >> 3) - (key >> 3) + 7) * 15 + ((q & 7) - (key & 7) + 7);
    biasbf[t3] = bfs(btab[idx * 4 + h] * 1.4426950408889634f);
  }
}

// ---------------- fused attention: 1 window / block, 8 waves ----------------
__global__ __launch_bounds__(512, 4) void attn_kernel(
    const float* __restrict__ x, const unsigned short* __restrict__ wqkvt,
    const unsigned short* __restrict__ wprojt, const unsigned short* __restrict__ biasbf,
    const float* __restrict__ bproj, float* __restrict__ out) {
  __shared__ char lds[65536];
  char* xs = lds;            // bf16 x tile [64 tok][128 ch]; reused as ao after B2
  char* Qs = lds + 16384;    // bf16 Q [64 tok][128 ch]
  char* Ks = lds + 32768;    // bf16 K [64 tok][128 ch]
  char* Vt = lds + 49152;    // bf16 V^T [128 d][64 key], key-permuted columns
  const int tid = threadIdx.x;
  const int w = tid >> 6;       // wave 0..7
  const int lane = tid & 63;
  const int g = lane >> 4;
  const int q15 = lane & 15;
  const int rs = (q15 & 7) << 4;  // XOR swizzle; all row indices == q15 (mod 8)
  const int h = w >> 1;           // attention: head
  const int qh = w & 1;           // attention: query half (32 queries)
  const size_t wbase = (size_t)blockIdx.x * 8192;
  const f32x4 zero4 = {0.f, 0.f, 0.f, 0.f};
  const char* wqb = (const char*)wqkvt;
  const char* wpb = (const char*)wprojt;

  // ---- x HBM loads first (longest pole) ----
  const int srow = tid >> 3;
  const int sc8 = (tid & 7);
  const float* xp = x + wbase + srow * 128 + sc8 * 16;
  f32x4 a0 = *(const f32x4*)(xp + 0), a1 = *(const f32x4*)(xp + 4);
  f32x4 a2 = *(const f32x4*)(xp + 8), a3 = *(const f32x4*)(xp + 12);

  // ---- hoisted qkv weight loads (L2-hot; latency hides under stage + B1) ----
  u16x8 wqa[4], wka[4], wva[4];
#pragma unroll
  for (int ks = 0; ks < 4; ++ks) {
    const int kb = ks * 64 + g * 16;
    wqa[ks] = *(const u16x8*)(wqb + (size_t)(w * 16 + q15) * 256 + kb);
    wka[ks] = *(const u16x8*)(wqb + (size_t)(128 + w * 16 + q15) * 256 + kb);
    wva[ks] = *(const u16x8*)(wqb + (size_t)(256 + w * 16 + q15) * 256 + kb);
  }

  // ---- bias frags (L2-hot) ----
  u16x4 bias[4][2];
#pragma unroll
  for (int mk = 0; mk < 4; ++mk)
#pragma unroll
    for (int nq = 0; nq < 2; ++nq)
      bias[mk][nq] = ((const u16x4*)biasbf)[(((h * 2 + qh) * 4 + mk) * 2 + nq) * 64 + lane];

  // ---- stage x: f32 -> bf16, swizzled [64 tok][128 ch] ----
  {
    uint4 p0, p1;
    p0.x = pk2n(a0[0], a0[1]); p0.y = pk2n(a0[2], a0[3]);
    p0.z = pk2n(a1[0], a1[1]); p0.w = pk2n(a1[2], a1[3]);
    p1.x = pk2n(a2[0], a2[1]); p1.y = pk2n(a2[2], a2[3]);
    p1.z = pk2n(a3[0], a3[1]); p1.w = pk2n(a3[2], a3[3]);
    int swz = (srow & 7) << 4;
    *(uint4*)(xs + srow * 256 + ((sc8 * 32 + 0)  ^ swz)) = p0;
    *(uint4*)(xs + srow * 256 + ((sc8 * 32 + 16) ^ swz)) = p1;
  }
  __syncthreads();  // B1: x tile visible

  // ---- qkv: wave w owns ch/d block w*16..w*16+15 for Q, K, V ----
  {
    f32x4 qa[4], ka[4], va[4];
#pragma unroll
    for (int t = 0; t < 4; ++t) { qa[t] = zero4; ka[t] = zero4; va[t] = zero4; }
#pragma unroll
    for (int ks = 0; ks < 4; ++ks) {
      u16x8 xb[4];
#pragma unroll
      for (int t = 0; t < 4; ++t)
        xb[t] = *(const u16x8*)(xs + (t * 16 + q15) * 256 + ((ks * 64 + g * 16) ^ rs));
      __builtin_amdgcn_s_setprio(1);
#pragma unroll
      for (int t = 0; t < 4; ++t) {
        qa[t] = mfma32(wqa[ks], xb[t], qa[t]);   // Q^T tile: rows=ch, col=tok
        ka[t] = mfma32(wka[ks], xb[t], ka[t]);   // K^T tile
        va[t] = mfma32(xb[t], wva[ks], va[t]);   // V tile: rows=tok, col=d
      }
      __builtin_amdgcn_s_setprio(0);
    }
    // stores: C-layout quad (4 rows, fixed col) -> contiguous 8B in [col][row] tiles
#pragma unroll
    for (int t = 0; t < 4; ++t) {
      int tok = t * 16 + q15;
      *(uint2*)(Qs + tok * 256 + ((w * 32 + g * 8) ^ rs)) = pku2(qa[t]);  // Q[tok][ch]
      *(uint2*)(Ks + tok * 256 + ((w * 32 + g * 8) ^ rs)) = pku2(ka[t]);  // K[tok][ch]
      // V^T[d][key]: key-permuted so a 16B read at (s2,g) yields bp8's k-slot order
      *(uint2*)(Vt + (w * 16 + q15) * 128 +
                ((((t >> 1) * 64 + g * 16) + (t & 1) * 8) ^ rs)) = pku2(va[t]);
    }
  }
  __syncthreads();  // B2: Q,K,V visible; xs dead -> reuse as ao

  // ---- attention: wave = (head h, query-half qh); 32 queries ----
  u16x8 kf[4], qf[2];
#pragma unroll
  for (int mk = 0; mk < 4; ++mk)
    kf[mk] = *(const u16x8*)(Ks + (mk * 16 + q15) * 256 + ((h * 64 + g * 16) ^ rs));
#pragma unroll
  for (int nq = 0; nq < 2; ++nq)
    qf[nq] = *(const u16x8*)(Qs + (qh * 32 + nq * 16 + q15) * 256 + ((h * 64 + g * 16) ^ rs));

  f32x4 st[4][2];
#pragma unroll
  for (int mk = 0; mk < 4; ++mk)
#pragma unroll
    for (int nq = 0; nq < 2; ++nq)
      st[mk][nq] = bf4up(bias[mk][nq]);
  __builtin_amdgcn_s_setprio(1);
#pragma unroll
  for (int mk = 0; mk < 4; ++mk)
#pragma unroll
    for (int nq = 0; nq < 2; ++nq)
      st[mk][nq] = mfma32(kf[mk], qf[nq], st[mk][nq]);  // S^T[key][q]
  __builtin_amdgcn_s_setprio(0);

  float rc[2];
#pragma unroll
  for (int nq = 0; nq < 2; ++nq) {
    float s = 0.f;
#pragma unroll
    for (int mk = 0; mk < 4; ++mk)
#pragma unroll
      for (int i = 0; i < 4; ++i) {
        float e = __builtin_amdgcn_exp2f(st[mk][nq][i]);
        st[mk][nq][i] = e;
        s += e;
      }
    s += __shfl_xor(s, 16);
    s += __shfl_xor(s, 32);
    rc[nq] = __builtin_amdgcn_rcpf(s);
  }
  u16x8 bp8[2][2];
#pragma unroll
  for (int s2 = 0; s2 < 2; ++s2)
#pragma unroll
    for (int nq = 0; nq < 2; ++nq)
      bp8[s2][nq] = pack8(st[2 * s2][nq], st[2 * s2 + 1][nq]);

  // PV: out^T[d][q] += V^T . P^T  (Vt's permuted columns match bp8 k-slots)
  f32x4 ot[2][2];
#pragma unroll
  for (int md = 0; md < 2; ++md)
#pragma unroll
    for (int nq = 0; nq < 2; ++nq) ot[md][nq] = zero4;
#pragma unroll
  for (int s2 = 0; s2 < 2; ++s2) {
    u16x8 vf[2];
#pragma unroll
    for (int md = 0; md < 2; ++md)
      vf[md] = *(const u16x8*)(Vt + (h * 32 + md * 16 + q15) * 128 +
                               ((s2 * 64 + g * 16) ^ rs));
    __builtin_amdgcn_s_setprio(1);
#pragma unroll
    for (int md = 0; md < 2; ++md)
#pragma unroll
      for (int nq = 0; nq < 2; ++nq)
        ot[md][nq] = mfma32(vf[md], bp8[s2][nq], ot[md][nq]);
    __builtin_amdgcn_s_setprio(0);
  }

  // ---- stage normalized attn-out into ao (= xs) ----
  char* ao = xs;
#pragma unroll
  for (int md = 0; md < 2; ++md)
#pragma unroll
    for (int nq = 0; nq < 2; ++nq) {
      int q = qh * 32 + nq * 16 + q15;
      f32x4 v = ot[md][nq];
      uint2 w2;
      w2.x = pk2n(v[0] * rc[nq], v[1] * rc[nq]);
      w2.y = pk2n(v[2] * rc[nq], v[3] * rc[nq]);
      *(uint2*)(ao + q * 256 + ((h * 64 + md * 32 + g * 8) ^ rs)) = w2;
    }

  // ---- prefetch proj weights/bias BEFORE the barrier ----
  u16x8 wpf[4];
#pragma unroll
  for (int ks = 0; ks < 4; ++ks)
    wpf[ks] = *(const u16x8*)(wpb + (size_t)(w * 16 + q15) * 256 + ks * 64 + g * 16);
  f32x4 bv = *(const f32x4*)(bproj + w * 16 + g * 4);
  __syncthreads();  // B3: ao complete

  // ---- proj: wave w owns c_out block w*16; po = Wp^T . ao^T -> [c_out][tok] ----
  f32x4 po[4];
#pragma unroll
  for (int t = 0; t < 4; ++t) po[t] = zero4;
#pragma unroll
  for (int ks = 0; ks < 4; ++ks) {
    u16x8 axb[4];
#pragma unroll
    for (int t = 0; t < 4; ++t)
      axb[t] = *(const u16x8*)(ao + (t * 16 + q15) * 256 + ((ks * 64 + g * 16) ^ rs));
    __builtin_amdgcn_s_setprio(1);
#pragma unroll
    for (int t = 0; t < 4; ++t)
      po[t] = mfma32(wpf[ks], axb[t], po[t]);
    __builtin_amdgcn_s_setprio(0);
  }
  float* op = out + wbase;
#pragma unroll
  for (int t = 0; t < 4; ++t) {
    f32x4 vs = po[t] + bv;
    *(f32x4*)(op + (size_t)(t * 16 + q15) * 128 + w * 16 + g * 4) = vs;
  }
}

extern "C" void kernel_launch(void* const* d_in, const int* in_sizes, int n_in,
                              void* d_out, int out_size, void* d_ws, size_t ws_size,
                              hipStream_t stream) {
  const float* x     = (const float*)d_in[0];
  const float* wqkv  = (const float*)d_in[1];
  const float* wproj = (const float*)d_in[2];
  const float* bproj = (const float*)d_in[3];
  const float* btab  = (const float*)d_in[4];
  char* ws = (char*)d_ws;
  unsigned short* wqkvt  = (unsigned short*)ws;             // 98304 B
  unsigned short* wprojt = (unsigned short*)(ws + 98304);   // 32768 B
  unsigned short* biasbf = (unsigned short*)(ws + 131072);  // 32768 B

  prep_kernel<<<320, 256, 0, stream>>>(wqkv, wproj, btab, wqkvt, wprojt, biasbf);
  attn_kernel<<<4096, 512, 0, stream>>>(x, wqkvt, wprojt, biasbf, bproj, (float*)d_out);
}

// Round 22
// 100.393 us; speedup vs baseline: 1.0480x; 1.0480x over previous
//
#include <hip/hip_runtime.h>
#include <cstdint>
#include <cstddef>

// Fused Swin-style window attention for MI355X (gfx950), round 22 = R20 verbatim.
// R21 lesson: hoisting qkv weights spilled (WRITE 131->139MB, 105us) -- inline
// loads were already optimal. R20 is the measured optimum of this landscape:
// R17 8-wave LDS-mediated structure (512 thr, 64KB, 3 barriers, 2 blocks/CU)
// + s_setprio around MFMA clusters + raw v_exp_f32 + x-loads-first ordering.
// Every mapped direction regresses: reg-capped occupancy (spill), smaller LDS
// (barrier tax), 16-wave blocks (HW cap), multi-window pipelines (spill),
// deferred normalization (wrong across heads), weight hoist (spill).

typedef float f32x4 __attribute__((ext_vector_type(4)));
typedef __bf16 bf16x8 __attribute__((ext_vector_type(8)));
typedef unsigned short u16x8 __attribute__((ext_vector_type(8)));
typedef unsigned short u16x4 __attribute__((ext_vector_type(4)));

__device__ __forceinline__ unsigned short bfs(float f) {
  return __builtin_bit_cast(unsigned short, (__bf16)f);  // HW RNE cvt
}
__device__ __forceinline__ unsigned pk2n(float a, float b) {
  return (unsigned)bfs(a) | ((unsigned)bfs(b) << 16);
}
__device__ __forceinline__ uint2 pku2(f32x4 v) {
  uint2 r; r.x = pk2n(v[0], v[1]); r.y = pk2n(v[2], v[3]); return r;
}
__device__ __forceinline__ u16x8 pack8(f32x4 a, f32x4 b) {
  u16x8 r;
  r[0] = bfs(a[0]); r[1] = bfs(a[1]); r[2] = bfs(a[2]); r[3] = bfs(a[3]);
  r[4] = bfs(b[0]); r[5] = bfs(b[1]); r[6] = bfs(b[2]); r[7] = bfs(b[3]);
  return r;
}
__device__ __forceinline__ f32x4 bf4up(u16x4 v) {
  f32x4 r;
  r[0] = __builtin_bit_cast(float, (unsigned)v[0] << 16);
  r[1] = __builtin_bit_cast(float, (unsigned)v[1] << 16);
  r[2] = __builtin_bit_cast(float, (unsigned)v[2] << 16);
  r[3] = __builtin_bit_cast(float, (unsigned)v[3] << 16);
  return r;
}
__device__ __forceinline__ f32x4 mfma32(u16x8 a, u16x8 b, f32x4 c) {
  return __builtin_amdgcn_mfma_f32_16x16x32_bf16(
      __builtin_bit_cast(bf16x8, a), __builtin_bit_cast(bf16x8, b), c, 0, 0, 0);
}

// ---------------- prep: weights^T -> bf16, rel-pos bias -> bf16 frag layout ----------
// ws: [0,98304)        wqkv_t bf16 [384 cols][128 k]   (Q cols scaled by log2e/sqrt(hd))
//     [98304,131072)   wproj_t bf16 [128 cols][128 k]
//     [131072,163840)  bias bf16 [h][qh][mk][nq][lane][i]  (S^T frag layout, * log2e)
__global__ void prep_kernel(const float* __restrict__ wqkv, const float* __restrict__ wproj,
                            const float* __restrict__ btab,
                            unsigned short* __restrict__ wqkvt,
                            unsigned short* __restrict__ wprojt,
                            unsigned short* __restrict__ biasbf) {
  int t = blockIdx.x * 256 + threadIdx.x;
  if (t < 49152) {
    int c = t >> 7, k = t & 127;
    float v = wqkv[k * 384 + c];
    if (c < 128) v *= 0.25503486f;  // log2(e)/sqrt(32)
    wqkvt[t] = bfs(v);
  } else if (t < 65536) {
    int t2 = t - 49152;
    int c = t2 >> 7, k = t2 & 127;
    wprojt[t2] = bfs(wproj[k * 128 + c]);
  } else if (t < 81920) {
    int t3 = t - 65536;
    int i = t3 & 3, lane = (t3 >> 2) & 63;
    int nq = (t3 >> 8) & 1, mk = (t3 >> 9) & 3, qh = (t3 >> 11) & 1, h = (t3 >> 12) & 3;
    int key = mk * 16 + ((lane >> 4) << 2) + i;      // S^T row (C-layout)
    int q   = qh * 32 + nq * 16 + (lane & 15);       // S^T col
    int idx = ((q >> 3) - (key >> 3) + 7) * 15 + ((q & 7) - (key & 7) + 7);
    biasbf[t3] = bfs(btab[idx * 4 + h] * 1.4426950408889634f);
  }
}

// ---------------- fused attention: 1 window / block, 8 waves ----------------
__global__ __launch_bounds__(512, 4) void attn_kernel(
    const float* __restrict__ x, const unsigned short* __restrict__ wqkvt,
    const unsigned short* __restrict__ wprojt, const unsigned short* __restrict__ biasbf,
    const float* __restrict__ bproj, float* __restrict__ out) {
  __shared__ char lds[65536];
  char* xs = lds;            // bf16 x tile [64 tok][128 ch]; reused as ao after B2
  char* Qs = lds + 16384;    // bf16 Q [64 tok][128 ch]
  char* Ks = lds + 32768;    // bf16 K [64 tok][128 ch]
  char* Vt = lds + 49152;    // bf16 V^T [128 d][64 key], key-permuted columns
  const int tid = threadIdx.x;
  const int w = tid >> 6;       // wave 0..7
  const int lane = tid & 63;
  const int g = lane >> 4;
  const int q15 = lane & 15;
  const int rs = (q15 & 7) << 4;  // XOR swizzle; all row indices == q15 (mod 8)
  const int h = w >> 1;           // attention: head
  const int qh = w & 1;           // attention: query half (32 queries)
  const size_t wbase = (size_t)blockIdx.x * 8192;
  const f32x4 zero4 = {0.f, 0.f, 0.f, 0.f};
  const char* wqb = (const char*)wqkvt;
  const char* wpb = (const char*)wprojt;

  // ---- x HBM loads first (longest pole), then bias L2 loads ----
  const int srow = tid >> 3;
  const int sc8 = (tid & 7);
  const float* xp = x + wbase + srow * 128 + sc8 * 16;
  f32x4 a0 = *(const f32x4*)(xp + 0), a1 = *(const f32x4*)(xp + 4);
  f32x4 a2 = *(const f32x4*)(xp + 8), a3 = *(const f32x4*)(xp + 12);

  u16x4 bias[4][2];
#pragma unroll
  for (int mk = 0; mk < 4; ++mk)
#pragma unroll
    for (int nq = 0; nq < 2; ++nq)
      bias[mk][nq] = ((const u16x4*)biasbf)[(((h * 2 + qh) * 4 + mk) * 2 + nq) * 64 + lane];

  // ---- stage x: f32 -> bf16, swizzled [64 tok][128 ch] ----
  {
    uint4 p0, p1;
    p0.x = pk2n(a0[0], a0[1]); p0.y = pk2n(a0[2], a0[3]);
    p0.z = pk2n(a1[0], a1[1]); p0.w = pk2n(a1[2], a1[3]);
    p1.x = pk2n(a2[0], a2[1]); p1.y = pk2n(a2[2], a2[3]);
    p1.z = pk2n(a3[0], a3[1]); p1.w = pk2n(a3[2], a3[3]);
    int swz = (srow & 7) << 4;
    *(uint4*)(xs + srow * 256 + ((sc8 * 32 + 0)  ^ swz)) = p0;
    *(uint4*)(xs + srow * 256 + ((sc8 * 32 + 16) ^ swz)) = p1;
  }
  __syncthreads();  // B1: x tile visible

  // ---- qkv: wave w owns ch/d block w*16..w*16+15 for Q, K, V ----
  {
    f32x4 qa[4], ka[4], va[4];
#pragma unroll
    for (int t = 0; t < 4; ++t) { qa[t] = zero4; ka[t] = zero4; va[t] = zero4; }
#pragma unroll
    for (int ks = 0; ks < 4; ++ks) {
      u16x8 xb[4];
#pragma unroll
      for (int t = 0; t < 4; ++t)
        xb[t] = *(const u16x8*)(xs + (t * 16 + q15) * 256 + ((ks * 64 + g * 16) ^ rs));
      const int kb = ks * 64 + g * 16;
      u16x8 wqf = *(const u16x8*)(wqb + (size_t)(w * 16 + q15) * 256 + kb);
      u16x8 wkf = *(const u16x8*)(wqb + (size_t)(128 + w * 16 + q15) * 256 + kb);
      u16x8 wvf = *(const u16x8*)(wqb + (size_t)(256 + w * 16 + q15) * 256 + kb);
      __builtin_amdgcn_s_setprio(1);
#pragma unroll
      for (int t = 0; t < 4; ++t) {
        qa[t] = mfma32(wqf, xb[t], qa[t]);   // Q^T tile: rows=ch, col=tok
        ka[t] = mfma32(wkf, xb[t], ka[t]);   // K^T tile
        va[t] = mfma32(xb[t], wvf, va[t]);   // V tile: rows=tok, col=d
      }
      __builtin_amdgcn_s_setprio(0);
    }
    // stores: C-layout quad (4 rows, fixed col) -> contiguous 8B in [col][row] tiles
#pragma unroll
    for (int t = 0; t < 4; ++t) {
      int tok = t * 16 + q15;
      *(uint2*)(Qs + tok * 256 + ((w * 32 + g * 8) ^ rs)) = pku2(qa[t]);  // Q[tok][ch]
      *(uint2*)(Ks + tok * 256 + ((w * 32 + g * 8) ^ rs)) = pku2(ka[t]);  // K[tok][ch]
      // V^T[d][key]: key-permuted so a 16B read at (s2,g) yields bp8's k-slot order
      *(uint2*)(Vt + (w * 16 + q15) * 128 +
                ((((t >> 1) * 64 + g * 16) + (t & 1) * 8) ^ rs)) = pku2(va[t]);
    }
  }
  __syncthreads();  // B2: Q,K,V visible; xs dead -> reuse as ao

  // ---- attention: wave = (head h, query-half qh); 32 queries ----
  u16x8 kf[4], qf[2];
#pragma unroll
  for (int mk = 0; mk < 4; ++mk)
    kf[mk] = *(const u16x8*)(Ks + (mk * 16 + q15) * 256 + ((h * 64 + g * 16) ^ rs));
#pragma unroll
  for (int nq = 0; nq < 2; ++nq)
    qf[nq] = *(const u16x8*)(Qs + (qh * 32 + nq * 16 + q15) * 256 + ((h * 64 + g * 16) ^ rs));

  f32x4 st[4][2];
#pragma unroll
  for (int mk = 0; mk < 4; ++mk)
#pragma unroll
    for (int nq = 0; nq < 2; ++nq)
      st[mk][nq] = bf4up(bias[mk][nq]);
  __builtin_amdgcn_s_setprio(1);
#pragma unroll
  for (int mk = 0; mk < 4; ++mk)
#pragma unroll
    for (int nq = 0; nq < 2; ++nq)
      st[mk][nq] = mfma32(kf[mk], qf[nq], st[mk][nq]);  // S^T[key][q]
  __builtin_amdgcn_s_setprio(0);

  float rc[2];
#pragma unroll
  for (int nq = 0; nq < 2; ++nq) {
    float s = 0.f;
#pragma unroll
    for (int mk = 0; mk < 4; ++mk)
#pragma unroll
      for (int i = 0; i < 4; ++i) {
        float e = __builtin_amdgcn_exp2f(st[mk][nq][i]);
        st[mk][nq][i] = e;
        s += e;
      }
    s += __shfl_xor(s, 16);
    s += __shfl_xor(s, 32);
    rc[nq] = __builtin_amdgcn_rcpf(s);
  }
  u16x8 bp8[2][2];
#pragma unroll
  for (int s2 = 0; s2 < 2; ++s2)
#pragma unroll
    for (int nq = 0; nq < 2; ++nq)
      bp8[s2][nq] = pack8(st[2 * s2][nq], st[2 * s2 + 1][nq]);

  // PV: out^T[d][q] += V^T . P^T  (Vt's permuted columns match bp8 k-slots)
  f32x4 ot[2][2];
#pragma unroll
  for (int md = 0; md < 2; ++md)
#pragma unroll
    for (int nq = 0; nq < 2; ++nq) ot[md][nq] = zero4;
#pragma unroll
  for (int s2 = 0; s2 < 2; ++s2) {
    u16x8 vf[2];
#pragma unroll
    for (int md = 0; md < 2; ++md)
      vf[md] = *(const u16x8*)(Vt + (h * 32 + md * 16 + q15) * 128 +
                               ((s2 * 64 + g * 16) ^ rs));
    __builtin_amdgcn_s_setprio(1);
#pragma unroll
    for (int md = 0; md < 2; ++md)
#pragma unroll
      for (int nq = 0; nq < 2; ++nq)
        ot[md][nq] = mfma32(vf[md], bp8[s2][nq], ot[md][nq]);
    __builtin_amdgcn_s_setprio(0);
  }

  // ---- stage normalized attn-out into ao (= xs) ----
  char* ao = xs;
#pragma unroll
  for (int md = 0; md < 2; ++md)
#pragma unroll
    for (int nq = 0; nq < 2; ++nq) {
      int q = qh * 32 + nq * 16 + q15;
      f32x4 v = ot[md][nq];
      uint2 w2;
      w2.x = pk2n(v[0] * rc[nq], v[1] * rc[nq]);
      w2.y = pk2n(v[2] * rc[nq], v[3] * rc[nq]);
      *(uint2*)(ao + q * 256 + ((h * 64 + md * 32 + g * 8) ^ rs)) = w2;
    }

  // ---- prefetch proj weights/bias BEFORE the barrier ----
  u16x8 wpf[4];
#pragma unroll
  for (int ks = 0; ks < 4; ++ks)
    wpf[ks] = *(const u16x8*)(wpb + (size_t)(w * 16 + q15) * 256 + ks * 64 + g * 16);
  f32x4 bv = *(const f32x4*)(bproj + w * 16 + g * 4);
  __syncthreads();  // B3: ao complete

  // ---- proj: wave w owns c_out block w*16; po = Wp^T . ao^T -> [c_out][tok] ----
  f32x4 po[4];
#pragma unroll
  for (int t = 0; t < 4; ++t) po[t] = zero4;
#pragma unroll
  for (int ks = 0; ks < 4; ++ks) {
    u16x8 axb[4];
#pragma unroll
    for (int t = 0; t < 4; ++t)
      axb[t] = *(const u16x8*)(ao + (t * 16 + q15) * 256 + ((ks * 64 + g * 16) ^ rs));
    __builtin_amdgcn_s_setprio(1);
#pragma unroll
    for (int t = 0; t < 4; ++t)
      po[t] = mfma32(wpf[ks], axb[t], po[t]);
    __builtin_amdgcn_s_setprio(0);
  }
  float* op = out + wbase;
#pragma unroll
  for (int t = 0; t < 4; ++t) {
    f32x4 vs = po[t] + bv;
    *(f32x4*)(op + (size_t)(t * 16 + q15) * 128 + w * 16 + g * 4) = vs;
  }
}

extern "C" void kernel_launch(void* const* d_in, const int* in_sizes, int n_in,
                              void* d_out, int out_size, void* d_ws, size_t ws_size,
                              hipStream_t stream) {
  const float* x     = (const float*)d_in[0];
  const float* wqkv  = (const float*)d_in[1];
  const float* wproj = (const float*)d_in[2];
  const float* bproj = (const float*)d_in[3];
  const float* btab  = (const float*)d_in[4];
  char* ws = (char*)d_ws;
  unsigned short* wqkvt  = (unsigned short*)ws;             // 98304 B
  unsigned short* wprojt = (unsigned short*)(ws + 98304);   // 32768 B
  unsigned short* biasbf = (unsigned short*)(ws + 131072);  // 32768 B

  prep_kernel<<<320, 256, 0, stream>>>(wqkv, wproj, btab, wqkvt, wprojt, biasbf);
  attn_kernel<<<4096, 512, 0, stream>>>(x, wqkvt, wprojt, biasbf, bproj, (float*)d_out);
}